// Round 5
// baseline (241.972 us; speedup 1.0000x reference)
//
#include <hip/hip_runtime.h>

#define T_DIM 4096
#define C_DIM 512
#define E_DIM 1024
#define KW 15
#define LN_EPS 1e-5f

#define TB 16                 // output rows per corr block
#define RT (TB + KW - 1)      // rows touched per corr block = 30

// ---------------------------------------------------------------------------
// Prep: fold gamma/beta into the taps.
//   wpad[c][j]  = gamma[c] * w[c][j]          (j = 0..14)
//   wpad[c][15] = beta[c]  * sum_j w[c][j]
// ---------------------------------------------------------------------------
__global__ __launch_bounds__(512) void fgu_prep_kernel(
    const float* __restrict__ w,
    const float* __restrict__ gamma,
    const float* __restrict__ beta,
    float* __restrict__ wpad)
{
    const int c = threadIdx.x;           // one block of 512
    const float gm = gamma[c];
    const float bt = beta[c];
    float s = 0.0f;
    float* o = wpad + c * 16;
    #pragma unroll
    for (int j = 0; j < KW; ++j) {
        const float wj = w[c * KW + j];
        s += wj;
        o[j] = gm * wj;
    }
    o[KW] = bt * s;
}

// ---------------------------------------------------------------------------
// K_stats: per-row LN stats. One 64-lane wave per (b,t) row; 8 elems/lane.
// Writes (rsigma, -mu*rsigma) per row. Pure streaming, no barriers.
// ---------------------------------------------------------------------------
__global__ __launch_bounds__(256) void fgu_stats_kernel(
    const float* __restrict__ x,
    float2* __restrict__ stats)
{
    const int row  = (int)((blockIdx.x * blockDim.x + threadIdx.x) >> 6);
    const int lane = threadIdx.x & 63;

    const float* gp = x + (size_t)row * E_DIM + C_DIM;
    const float4 a  = *(const float4*)(gp + lane * 4);
    const float4 b4 = *(const float4*)(gp + 256 + lane * 4);

    float s  = a.x + a.y + a.z + a.w + b4.x + b4.y + b4.z + b4.w;
    float ss = a.x*a.x + a.y*a.y + a.z*a.z + a.w*a.w
             + b4.x*b4.x + b4.y*b4.y + b4.z*b4.z + b4.w*b4.w;
    #pragma unroll
    for (int off = 32; off; off >>= 1) {
        s  += __shfl_xor(s, off);
        ss += __shfl_xor(ss, off);
    }
    if (lane == 0) {
        const float mu  = s * (1.0f / (float)C_DIM);
        const float var = ss * (1.0f / (float)C_DIM) - mu * mu;
        const float rs  = rsqrtf(var + LN_EPS);
        stats[row] = make_float2(rs, -mu * rs);
    }
}

// ---------------------------------------------------------------------------
// K_corr: normalize (stats from ws) + 15-tap circular correlation + gate.
// 256 threads/block, 2 channels per thread (float2), TB=16 rows per block.
// No LDS, no barriers, no shuffles; stats loads are block-uniform (scalar).
// Gate rows are L3-hot (just streamed by K_stats).
// ---------------------------------------------------------------------------
__global__ __launch_bounds__(256) void fgu_corr_kernel(
    const float* __restrict__ x,
    const float2* __restrict__ stats,
    const float* __restrict__ wpad,
    float* __restrict__ out)
{
    const int tid = threadIdx.x;                 // 0..255
    const int b   = blockIdx.x >> 8;             // T_DIM/TB = 256 tiles per b
    const int t0  = (blockIdx.x & 255) * TB;
    const int c   = tid * 2;                     // channel pair (c, c+1)

    const float* xb = x + (size_t)b * T_DIM * E_DIM;
    const float2* sb = stats + ((size_t)b << 12);

    // Gate loads (independent, in flight together) + normalize.
    float2 z[RT];
    const float* gc = xb + C_DIM + c;
    #pragma unroll
    for (int k = 0; k < RT; ++k) {
        const int tt = (t0 + k) & (T_DIM - 1);
        const float2 g = *(const float2*)(gc + (size_t)tt * E_DIM);
        const float2 p = sb[tt];                 // uniform across block
        z[k].x = fmaf(g.x, p.x, p.y);
        z[k].y = fmaf(g.y, p.x, p.y);
    }

    // Folded taps for both channels.
    float wr0[16], wr1[16];
    {
        const float4* wp = (const float4*)(wpad + c * 16);
        #pragma unroll
        for (int q = 0; q < 4; ++q) {
            const float4 v0 = wp[q];
            const float4 v1 = wp[q + 4];
            wr0[q*4+0] = v0.x; wr0[q*4+1] = v0.y; wr0[q*4+2] = v0.z; wr0[q*4+3] = v0.w;
            wr1[q*4+0] = v1.x; wr1[q*4+1] = v1.y; wr1[q*4+2] = v1.z; wr1[q*4+3] = v1.w;
        }
    }

    const float* rb = xb + (size_t)t0 * E_DIM + c;                 // residual
    float*       ob = out + ((size_t)b * T_DIM + t0) * C_DIM + c;
    #pragma unroll
    for (int i = 0; i < TB; ++i) {
        float a0 = wr0[KW];                      // beta * sum(w) bias
        float a1 = wr1[KW];
        #pragma unroll
        for (int j = 0; j < KW; ++j) {
            a0 = fmaf(z[i + j].x, wr0[j], a0);
            a1 = fmaf(z[i + j].y, wr1[j], a1);
        }
        const float2 r = *(const float2*)(rb + (size_t)i * E_DIM);
        *(float2*)(ob + (size_t)i * C_DIM) = make_float2(r.x * a0, r.y * a1);
    }
}

extern "C" void kernel_launch(void* const* d_in, const int* in_sizes, int n_in,
                              void* d_out, int out_size, void* d_ws, size_t ws_size,
                              hipStream_t stream) {
    const float* x      = (const float*)d_in[0];   // [8, 4096, 1024]
    const float* weight = (const float*)d_in[1];   // [512, 15]
    const float* gamma  = (const float*)d_in[2];   // [512]
    const float* beta   = (const float*)d_in[3];   // [512]
    float* out = (float*)d_out;                    // [8, 4096, 512]

    float*  wpad  = (float*)d_ws;                  // [512][16] = 32 KB
    float2* stats = (float2*)((char*)d_ws + 512 * 16 * sizeof(float)); // 32768 float2

    fgu_prep_kernel<<<1, 512, 0, stream>>>(weight, gamma, beta, wpad);

    const int nrows = 8 * T_DIM;                   // 32768
    fgu_stats_kernel<<<nrows / 4, 256, 0, stream>>>(x, stats);

    const int nblocks = 8 * (T_DIM / TB);          // 2048
    fgu_corr_kernel<<<nblocks, 256, 0, stream>>>(x, stats, wpad, out);
}